// Round 1
// baseline (628.094 us; speedup 1.0000x reference)
//
#include <hip/hip_runtime.h>
#include <math.h>

#define NN 50000
#define NE 800000
#define FIN 128
#define HID 64
#define HEADS 4
#define C1 256   // HEADS*HID
#define CLS 40
#define EPSF 1e-16f

// ---------------- counting sort of edges by dst ----------------

__global__ void k_zero(int* a, int n) {
    int i = blockIdx.x * 256 + threadIdx.x;
    if (i < n) a[i] = 0;
}

__global__ void k_hist(const int* __restrict__ ei, int* __restrict__ counts) {
    int i = blockIdx.x * 256 + threadIdx.x;
    if (i < NE) atomicAdd(&counts[ei[NE + i]], 1);
}

__global__ __launch_bounds__(1024) void k_scan1(const int* __restrict__ counts,
                                                int* __restrict__ offs,
                                                int* __restrict__ partials) {
    __shared__ int s[1024];
    int t = threadIdx.x;
    int g = blockIdx.x * 1024 + t;
    int v = (g < NN) ? counts[g] : 0;
    s[t] = v;
    __syncthreads();
    for (int d = 1; d < 1024; d <<= 1) {
        int x = (t >= d) ? s[t - d] : 0;
        __syncthreads();
        s[t] += x;
        __syncthreads();
    }
    if (g < NN) offs[g] = s[t] - v;           // block-local exclusive
    if (t == 1023) partials[blockIdx.x] = s[t]; // block total
}

__global__ void k_scan2(int* partials, int nb) {
    if (threadIdx.x == 0 && blockIdx.x == 0) {
        int run = 0;
        for (int b = 0; b < nb; b++) { int v = partials[b]; partials[b] = run; run += v; }
    }
}

__global__ void k_scan3(int* __restrict__ offs, const int* __restrict__ partials,
                        int* __restrict__ cursor) {
    int g = blockIdx.x * 256 + threadIdx.x;
    if (g < NN) {
        int o = offs[g] + partials[g >> 10];
        offs[g] = o;
        cursor[g] = o;
    }
}

__global__ void k_scatter(const int* __restrict__ ei, int* __restrict__ cursor,
                          int* __restrict__ ssrc) {
    int i = blockIdx.x * 256 + threadIdx.x;
    if (i < NE) {
        int s = ei[i];
        int d = ei[NE + i];
        int p = atomicAdd(&cursor[d], 1);
        ssrc[p] = s;
    }
}

// ---------------- layer 1 ----------------

// h1[m, n] = sum_k x[m,k] * W1[k,n];  16 rows/block, 256 cols (thread = col)
__global__ __launch_bounds__(256) void k_gemm1(const float* __restrict__ x,
                                               const float* __restrict__ W,
                                               float* __restrict__ h1) {
    int n = threadIdx.x;
    int m0 = blockIdx.x * 16;
    float acc[16];
#pragma unroll
    for (int r = 0; r < 16; r++) acc[r] = 0.f;
    const float* xr = x + (size_t)m0 * FIN;
#pragma unroll 4
    for (int k = 0; k < FIN; k++) {
        float w = W[k * C1 + n];
#pragma unroll
        for (int r = 0; r < 16; r++) acc[r] = fmaf(xr[r * FIN + k], w, acc[r]);
    }
#pragma unroll
    for (int r = 0; r < 16; r++) h1[(size_t)(m0 + r) * C1 + n] = acc[r];
}

// per-node attention dots: as1[n,h] = <h1[n,h,:], a_src1[h,:]>, same for ad1
__global__ __launch_bounds__(256) void k_alpha1(const float* __restrict__ h1,
                                                const float* __restrict__ aws,
                                                const float* __restrict__ awd,
                                                float* __restrict__ as1,
                                                float* __restrict__ ad1) {
    int n = blockIdx.x;
    int t = threadIdx.x;
    float h = h1[(size_t)n * C1 + t];
    float vs = h * aws[t];
    float vd = h * awd[t];
#pragma unroll
    for (int m = 32; m >= 1; m >>= 1) {
        vs += __shfl_xor(vs, m);
        vd += __shfl_xor(vd, m);
    }
    if ((t & 63) == 0) {
        int head = t >> 6;
        as1[n * 4 + head] = vs;
        ad1[n * 4 + head] = vd;
    }
}

// one wave per dst node; online softmax over its (sorted) incident edges.
// lane holds channels [4*lane .. 4*lane+3]; head = lane/16.
__global__ __launch_bounds__(256) void k_agg1(const float* __restrict__ h1,
                                              const float* __restrict__ as1,
                                              const float* __restrict__ ad1,
                                              const int* __restrict__ offs,
                                              const int* __restrict__ ssrc,
                                              const float* __restrict__ b1,
                                              float* __restrict__ g1) {
    int lane = threadIdx.x & 63;
    int node = blockIdx.x * 4 + (threadIdx.x >> 6);
    int head = lane >> 4;
    int beg = offs[node];
    int end = (node + 1 < NN) ? offs[node + 1] : NE;
    float adh = ad1[node * 4 + head];
    float m = -INFINITY, l = 0.f;
    float4 acc = {0.f, 0.f, 0.f, 0.f};
    const float4* h1v = (const float4*)h1;
    for (int j = beg; j < end; j++) {
        int src = ssrc[j];
        float e = as1[src * 4 + head] + adh;
        e = e > 0.f ? e : 0.2f * e;
        float nm = fmaxf(m, e);
        float sc = __expf(m - nm);
        float p = __expf(e - nm);
        m = nm;
        l = l * sc + p;
        float4 hv = h1v[(size_t)src * 64 + lane];
        acc.x = fmaf(p, hv.x, acc.x * sc);
        acc.y = fmaf(p, hv.y, acc.y * sc);
        acc.z = fmaf(p, hv.z, acc.z * sc);
        acc.w = fmaf(p, hv.w, acc.w * sc);
    }
    float inv = 1.f / (l + EPSF);
    const float4* b1v = (const float4*)b1;
    float4 b = b1v[lane];
    float4 o;
    o.x = fmaxf(fmaf(acc.x, inv, b.x), 0.f);
    o.y = fmaxf(fmaf(acc.y, inv, b.y), 0.f);
    o.z = fmaxf(fmaf(acc.z, inv, b.z), 0.f);
    o.w = fmaxf(fmaf(acc.w, inv, b.w), 0.f);
    ((float4*)g1)[(size_t)node * 64 + lane] = o;
}

// ---------------- layer 2 ----------------

// h2 = g1 @ W2  (50000x256 * 256x40). 16 rows/block: wave = 4 rows, lane = col.
__global__ __launch_bounds__(256) void k_gemm2(const float* __restrict__ g1,
                                               const float* __restrict__ W2,
                                               float* __restrict__ h2) {
    int t = threadIdx.x;
    int col = t & 63;
    int rg = t >> 6;
    int m0 = blockIdx.x * 16 + rg * 4;
    bool act = col < CLS;
    float acc[4] = {0.f, 0.f, 0.f, 0.f};
    const float* gr = g1 + (size_t)m0 * C1;
#pragma unroll 4
    for (int k = 0; k < C1; k++) {
        float w = act ? W2[k * CLS + col] : 0.f;
#pragma unroll
        for (int r = 0; r < 4; r++) acc[r] = fmaf(gr[r * C1 + k], w, acc[r]);
    }
    if (act) {
#pragma unroll
        for (int r = 0; r < 4; r++) h2[(size_t)(m0 + r) * CLS + col] = acc[r];
    }
}

__global__ void k_alpha2(const float* __restrict__ h2, const float* __restrict__ aws,
                         const float* __restrict__ awd, float* __restrict__ as2,
                         float* __restrict__ ad2) {
    int n = blockIdx.x * 256 + threadIdx.x;
    if (n < NN) {
        float s = 0.f, d = 0.f;
        for (int c = 0; c < CLS; c++) {
            float h = h2[(size_t)n * CLS + c];
            s = fmaf(h, aws[c], s);
            d = fmaf(h, awd[c], d);
        }
        as2[n] = s;
        ad2[n] = d;
    }
}

// wave per node: online-softmax aggregation over 40 channels + fused log_softmax
__global__ __launch_bounds__(256) void k_agg2(const float* __restrict__ h2,
                                              const float* __restrict__ as2,
                                              const float* __restrict__ ad2,
                                              const int* __restrict__ offs,
                                              const int* __restrict__ ssrc,
                                              const float* __restrict__ b2,
                                              float* __restrict__ out) {
    int lane = threadIdx.x & 63;
    int node = blockIdx.x * 4 + (threadIdx.x >> 6);
    int beg = offs[node];
    int end = (node + 1 < NN) ? offs[node + 1] : NE;
    float adh = ad2[node];
    bool act = lane < CLS;
    float m = -INFINITY, l = 0.f, acc = 0.f;
    for (int j = beg; j < end; j++) {
        int src = ssrc[j];
        float e = as2[src] + adh;
        e = e > 0.f ? e : 0.2f * e;
        float nm = fmaxf(m, e);
        float sc = __expf(m - nm);
        float p = __expf(e - nm);
        m = nm;
        l = l * sc + p;
        float hv = act ? h2[(size_t)src * CLS + lane] : 0.f;
        acc = fmaf(p, hv, acc * sc);
    }
    float v = act ? (acc / (l + EPSF) + b2[lane]) : -INFINITY;
    float mx = v;
#pragma unroll
    for (int s = 32; s >= 1; s >>= 1) mx = fmaxf(mx, __shfl_xor(mx, s));
    float ex = act ? __expf(v - mx) : 0.f;
    float sum = ex;
#pragma unroll
    for (int s = 32; s >= 1; s >>= 1) sum += __shfl_xor(sum, s);
    if (act) out[(size_t)node * CLS + lane] = v - mx - __logf(sum);
}

// ---------------- launch ----------------

extern "C" void kernel_launch(void* const* d_in, const int* in_sizes, int n_in,
                              void* d_out, int out_size, void* d_ws, size_t ws_size,
                              hipStream_t stream) {
    const float* x    = (const float*)d_in[0];
    const int*   ei   = (const int*)d_in[1];
    const float* W1   = (const float*)d_in[2];
    const float* as1w = (const float*)d_in[3];
    const float* ad1w = (const float*)d_in[4];
    const float* b1   = (const float*)d_in[5];
    const float* W2   = (const float*)d_in[6];
    const float* as2w = (const float*)d_in[7];
    const float* ad2w = (const float*)d_in[8];
    const float* b2   = (const float*)d_in[9];
    float* out = (float*)d_out;

    // workspace arena
    char* p = (char*)d_ws;
    auto alloc = [&](size_t bytes) {
        char* r = p;
        p += (bytes + 255) & ~(size_t)255;
        return r;
    };
    float* h1   = (float*)alloc((size_t)NN * C1 * 4);
    float* g1   = (float*)alloc((size_t)NN * C1 * 4);
    float* h2   = (float*)alloc((size_t)NN * CLS * 4);
    float* as1  = (float*)alloc((size_t)NN * 4 * 4);
    float* ad1  = (float*)alloc((size_t)NN * 4 * 4);
    float* as2  = (float*)alloc((size_t)NN * 4);
    float* ad2  = (float*)alloc((size_t)NN * 4);
    int* counts = (int*)alloc((size_t)NN * 4);
    int* offs   = (int*)alloc((size_t)NN * 4);
    int* cursor = (int*)alloc((size_t)NN * 4);
    int* parts  = (int*)alloc(64 * 4);
    int* ssrc   = (int*)alloc((size_t)NE * 4);

    const int nb_scan = (NN + 1023) / 1024;  // 49

    // edge sort by dst
    k_zero<<<(NN + 255) / 256, 256, 0, stream>>>(counts, NN);
    k_hist<<<(NE + 255) / 256, 256, 0, stream>>>(ei, counts);
    k_scan1<<<nb_scan, 1024, 0, stream>>>(counts, offs, parts);
    k_scan2<<<1, 64, 0, stream>>>(parts, nb_scan);
    k_scan3<<<(NN + 255) / 256, 256, 0, stream>>>(offs, parts, cursor);
    k_scatter<<<(NE + 255) / 256, 256, 0, stream>>>(ei, cursor, ssrc);

    // layer 1
    k_gemm1<<<NN / 16, 256, 0, stream>>>(x, W1, h1);
    k_alpha1<<<NN, 256, 0, stream>>>(h1, as1w, ad1w, as1, ad1);
    k_agg1<<<NN / 4, 256, 0, stream>>>(h1, as1, ad1, offs, ssrc, b1, g1);

    // layer 2
    k_gemm2<<<NN / 16, 256, 0, stream>>>(g1, W2, h2);
    k_alpha2<<<(NN + 255) / 256, 256, 0, stream>>>(h2, as2w, ad2w, as2, ad2);
    k_agg2<<<NN / 4, 256, 0, stream>>>(h2, as2, ad2, offs, ssrc, b2, out);
}